// Round 7
// baseline (205.805 us; speedup 1.0000x reference)
//
#include <hip/hip_runtime.h>
#include <hip/hip_bf16.h>

// Problem constants
#define B_   128
#define J_   2048
#define N_   32
#define D_   16
#define NJC  32       // j-chunks (64 j each); one s-partial per chunk

typedef __attribute__((ext_vector_type(8))) short short8b;   // 8 bf16 (4 VGPRs)
typedef __attribute__((ext_vector_type(4))) float f32x4;     // 16x16 MFMA acc
typedef __attribute__((ext_vector_type(16))) float f32x16;   // 32x32 MFMA acc

__device__ inline short bf16s(float f) {
    union { __hip_bfloat16 h; short s; } u;
    u.h = __float2bfloat16(f);
    return u.s;
}

// Workspace layout (float offsets):
//  xT     [0, 2097152)            xT[(j*128+b)*8 + p]          8 MB fp32
//  blogT  [2097152, 6291456)      blogT[(n*J+j)*128 + b]      16 MB bf16
//  mdT    [6291456, 6815744)      mdT[j*128 + b] float2        2 MB
//  s_part [6815744, 8912896)      [jc][b*512+n*16+d]           8 MB fp32
// total 34 MB

// ---------------------------------------------------------------------------
// T: xT[(j*128+b)*8+p] = x[b][j][p]   (LDS tile transpose)
// ---------------------------------------------------------------------------
__global__ __launch_bounds__(256) void capsT(const float* __restrict__ x,
                                             float* __restrict__ xT) {
    __shared__ float tile[32 * 260 + 4];
    const int t  = threadIdx.x;
    const int jt = blockIdx.x & 63;
    const int bt = blockIdx.x >> 6;
    const int j0 = jt * 32, b0 = bt * 32;

    for (int idx = t; idx < 2048; idx += 256) {
        int bl = idx >> 6, f4 = idx & 63;
        float4 v = *(const float4*)(x + (size_t)(b0 + bl) * 16384 + j0 * 8 + f4 * 4);
        *(float4*)&tile[bl * 260 + f4 * 4] = v;
    }
    __syncthreads();
    for (int idx = t; idx < 2048; idx += 256) {
        int jj = idx >> 6, f4o = idx & 63;
        int bl = f4o >> 1, po = (f4o & 1) * 4;
        float4 v = *(const float4*)&tile[bl * 260 + jj * 8 + po];
        *(float4*)(xT + ((size_t)(j0 + jj) * 128 + b0 + bl) * 8 + po) = v;
    }
}

// ---------------------------------------------------------------------------
// A (MFMA, unchanged from round 6): s_part[jc][b,n,d] = y(b,K) x W(K,d)
// ---------------------------------------------------------------------------
__global__ __launch_bounds__(256) void capsA(const float* __restrict__ W,
                                             const float* __restrict__ xT,
                                             const __hip_bfloat16* __restrict__ blogT,
                                             const float2* __restrict__ mdT,
                                             float* __restrict__ s_part,
                                             int mode) {
    const int t     = threadIdx.x;
    const int lane  = t & 63;
    const int i     = blockIdx.x;                    // 0..1023
    const int jc    = (i & 7) + 8 * (i >> 8);        // 0..31 (XCD-grouped)
    const int n     = (i >> 3) & 31;
    const int wv    = t >> 6;                        // 0..3
    const int colid = lane & 15;                     // d for B / b_low for A
    const int kgrp  = lane >> 4;                     // 0..3 -> j within K-step

    const int b0 = wv * 32 + colid;                  // A row, tile 0
    const int b1 = b0 + 16;                          // A row, tile 1

    f32x4 acc0 = {0.f, 0.f, 0.f, 0.f};
    f32x4 acc1 = {0.f, 0.f, 0.f, 0.f};

    for (int ks = 0; ks < 16; ++ks) {
        const int j = jc * 64 + ks * 4 + kgrp;       // per-lane j

        const float4* wp = (const float4*)(W + (((size_t)n * J_ + j) * 16 + colid) * 8);
        float4 wa = wp[0], wb = wp[1];
        short8b bfrag;
        bfrag[0] = bf16s(wa.x); bfrag[1] = bf16s(wa.y);
        bfrag[2] = bf16s(wa.z); bfrag[3] = bf16s(wa.w);
        bfrag[4] = bf16s(wb.x); bfrag[5] = bf16s(wb.y);
        bfrag[6] = bf16s(wb.z); bfrag[7] = bf16s(wb.w);

        float c0 = 1.0f / 32.0f, c1 = 1.0f / 32.0f;
        if (mode) {
            float lg0 = __bfloat162float(blogT[((size_t)n * J_ + j) * B_ + b0]);
            float lg1 = __bfloat162float(blogT[((size_t)n * J_ + j) * B_ + b1]);
            float2 m0 = mdT[(size_t)j * B_ + b0];
            float2 m1 = mdT[(size_t)j * B_ + b1];
            c0 = __expf(lg0 - m0.x) * m0.y;
            c1 = __expf(lg1 - m1.x) * m1.y;
        }

        const float4* xp0 = (const float4*)(xT + ((size_t)j * 128 + b0) * 8);
        float4 xa = xp0[0], xb = xp0[1];
        short8b afrag0;
        afrag0[0] = bf16s(xa.x * c0); afrag0[1] = bf16s(xa.y * c0);
        afrag0[2] = bf16s(xa.z * c0); afrag0[3] = bf16s(xa.w * c0);
        afrag0[4] = bf16s(xb.x * c0); afrag0[5] = bf16s(xb.y * c0);
        afrag0[6] = bf16s(xb.z * c0); afrag0[7] = bf16s(xb.w * c0);

        const float4* xp1 = (const float4*)(xT + ((size_t)j * 128 + b1) * 8);
        float4 xe = xp1[0], xf = xp1[1];
        short8b afrag1;
        afrag1[0] = bf16s(xe.x * c1); afrag1[1] = bf16s(xe.y * c1);
        afrag1[2] = bf16s(xe.z * c1); afrag1[3] = bf16s(xe.w * c1);
        afrag1[4] = bf16s(xf.x * c1); afrag1[5] = bf16s(xf.y * c1);
        afrag1[6] = bf16s(xf.z * c1); afrag1[7] = bf16s(xf.w * c1);

        acc0 = __builtin_amdgcn_mfma_f32_16x16x32_bf16(afrag0, bfrag, acc0, 0, 0, 0);
        acc1 = __builtin_amdgcn_mfma_f32_16x16x32_bf16(afrag1, bfrag, acc1, 0, 0, 0);
    }

    float* sdst = s_part + (size_t)jc * (B_ * N_ * D_);
    #pragma unroll
    for (int r = 0; r < 4; ++r) {
        int brow = wv * 32 + kgrp * 4 + r;
        sdst[(size_t)brow * 512 + n * 16 + colid]        = acc0[r];
        sdst[(size_t)(brow + 16) * 512 + n * 16 + colid] = acc1[r];
    }
}

// ---------------------------------------------------------------------------
// R: out[b,n,d] = squash(sum_jc s_part + bias)
// ---------------------------------------------------------------------------
__global__ __launch_bounds__(256) void capsR(const float* __restrict__ s_part,
                                             const float* __restrict__ bias,
                                             float* __restrict__ out) {
    int gid = blockIdx.x * 256 + threadIdx.x;       // 65536: b*512 + n*16 + d
    float sv = bias[gid & 511];
    #pragma unroll
    for (int jc = 0; jc < NJC; ++jc)
        sv += s_part[(size_t)jc * 65536 + gid];
    float sq = sv * sv;
    sq += __shfl_xor(sq, 1);
    sq += __shfl_xor(sq, 2);
    sq += __shfl_xor(sq, 4);
    sq += __shfl_xor(sq, 8);
    float scale = sq / (1.0f + sq) / sqrtf(sq + 1e-7f);
    out[gid] = scale * sv;
}

// ---------------------------------------------------------------------------
// B (MFMA): per (n, jc): V[(j,p),b] = sum_d W[n,j,d,p] * o[b,n,d]  via
//   mfma_f32_32x32x16_bf16 (M=32 rows = 4j x 8p, N=32 b, K=16 d), then
//   blog[b,j] = sum_p V[(j,p),b]*x[b,j,p]: 4 FMA on the D-frag + shfl_xor(32).
//   D layout (m74/m101): col=lane&31 (b), row=(reg&3)+8*(reg>>2)+4*(lane>>5)
//   -> row = r + 8*jl2 + 4g = jl2*8 + (r+4g): j-index = reg>>2, p = (reg&3)+4g.
//   256 thr = 4 waves x 16 j; 4 b-tiles of 32 per MFMA group; no LDS.
// ---------------------------------------------------------------------------
__global__ __launch_bounds__(256) void capsB(const float* __restrict__ W,
                                             const float* __restrict__ xT,
                                             const float* __restrict__ o,
                                             __hip_bfloat16* __restrict__ blogT,
                                             int accumulate) {
    const int t    = threadIdx.x;
    const int lane = t & 63;
    const int i    = blockIdx.x;                         // 0..1023
    const int jc   = (i & 7) + 8 * (i >> 8);             // 0..31 (XCD-grouped)
    const int n    = (i >> 3) & 31;
    const int wv   = t >> 6;                             // 0..3
    const int g    = lane >> 5;                          // k-half (d 0-7 / 8-15)
    const int col  = lane & 31;

    // ---- B-fragments: o[b = bt*32+col][n][d = g*8 .. g*8+7] (2x float4, once) ----
    short8b bfrag[4];
    #pragma unroll
    for (int bt = 0; bt < 4; ++bt) {
        const float4* op =
            (const float4*)(o + ((size_t)(bt * 32 + col) * N_ + n) * 16 + g * 8);
        float4 oa = op[0], ob = op[1];
        bfrag[bt][0] = bf16s(oa.x); bfrag[bt][1] = bf16s(oa.y);
        bfrag[bt][2] = bf16s(oa.z); bfrag[bt][3] = bf16s(oa.w);
        bfrag[bt][4] = bf16s(ob.x); bfrag[bt][5] = bf16s(ob.y);
        bfrag[bt][6] = bf16s(ob.z); bfrag[bt][7] = bf16s(ob.w);
    }

    const int jl = col >> 3;          // A-row: j within 4-j group
    const int p  = col & 7;           // A-row: p

    for (int jg = 0; jg < 4; ++jg) {
        const int j0 = jc * 64 + wv * 16 + jg * 4;

        // ---- A-fragment: W[n][j0+jl][d = g*8+q][p], q=0..7 (stride-8 dwords) ----
        const float* wbase = W + ((size_t)n * J_ + j0 + jl) * 128 + p + (size_t)g * 64;
        short8b afrag;
        #pragma unroll
        for (int q = 0; q < 8; ++q)
            afrag[q] = bf16s(wbase[q * 8]);

        f32x16 zz;
        #pragma unroll
        for (int q = 0; q < 16; ++q) zz[q] = 0.0f;

        f32x16 acc[4];
        #pragma unroll
        for (int bt = 0; bt < 4; ++bt)
            acc[bt] = __builtin_amdgcn_mfma_f32_32x32x16_bf16(afrag, bfrag[bt], zz, 0, 0, 0);

        // ---- epilogue: blog[b, j0+jl2] = sum_p V*x ----
        #pragma unroll
        for (int bt = 0; bt < 4; ++bt) {
            const int b = bt * 32 + col;
            #pragma unroll
            for (int jl2 = 0; jl2 < 4; ++jl2) {
                const int j = j0 + jl2;
                // lane's rows for this jl2: p = (r + 4g), r=0..3 -> x float4 at +g*4
                float4 xv = *(const float4*)(xT + ((size_t)j * 128 + b) * 8 + g * 4);
                float tt = acc[bt][jl2 * 4 + 0] * xv.x
                         + acc[bt][jl2 * 4 + 1] * xv.y
                         + acc[bt][jl2 * 4 + 2] * xv.z
                         + acc[bt][jl2 * 4 + 3] * xv.w;
                tt += __shfl_xor(tt, 32);                 // combine d.. p halves
                if (g == (jl2 >> 1)) {                    // write-split across halves
                    size_t a0 = ((size_t)n * J_ + j) * B_ + b;
                    if (accumulate) tt += __bfloat162float(blogT[a0]);
                    blogT[a0] = __float2bfloat16(tt);
                }
            }
        }
    }
}

// ---------------------------------------------------------------------------
// D: per (j,b): m = max_n blogT, inv = 1/sum_n exp(blogT-m)
// ---------------------------------------------------------------------------
__global__ __launch_bounds__(256) void capsD(const __hip_bfloat16* __restrict__ blogT,
                                             float2* __restrict__ mdT) {
    int gid = blockIdx.x * 256 + threadIdx.x;   // 262144 = J_*B_
    float v[32];
    float m = -1e30f;
    #pragma unroll
    for (int nn = 0; nn < 32; ++nn) {
        v[nn] = __bfloat162float(blogT[(size_t)nn * (J_ * B_) + gid]);
        m = fmaxf(m, v[nn]);
    }
    float sum = 0.0f;
    #pragma unroll
    for (int nn = 0; nn < 32; ++nn) sum += __expf(v[nn] - m);
    mdT[gid] = make_float2(m, 1.0f / sum);
}

// ---------------------------------------------------------------------------
extern "C" void kernel_launch(void* const* d_in, const int* in_sizes, int n_in,
                              void* d_out, int out_size, void* d_ws, size_t ws_size,
                              hipStream_t stream) {
    const float* x    = (const float*)d_in[0];   // [128,2048,8]
    const float* W    = (const float*)d_in[1];   // [32,2048,16,8]
    const float* bias = (const float*)d_in[2];   // [32,16]
    float* out = (float*)d_out;                  // [128,32,16]

    float* ws = (float*)d_ws;
    float*           xT     = ws;                                   // 8 MB
    __hip_bfloat16*  blogT  = (__hip_bfloat16*)(ws + 2097152);      // 16 MB bf16
    float2*          mdT    = (float2*)(ws + 2097152 + 4194304);    // 2 MB
    float*           s_part = ws + 2097152 + 4194304 + 524288;      // 8 MB

    dim3 b256(256);

    capsT<<<dim3(256), b256, 0, stream>>>(x, xT);

    // ---- routing iteration 0 (c uniform) ----
    capsA<<<dim3(1024), b256, 0, stream>>>(W, xT, blogT, mdT, s_part, 0);
    capsR<<<dim3(256), b256, 0, stream>>>(s_part, bias, out);
    capsB<<<dim3(1024), b256, 0, stream>>>(W, xT, out, blogT, 0);

    // ---- routing iteration 1 ----
    capsD<<<dim3(1024), b256, 0, stream>>>(blogT, mdT);
    capsA<<<dim3(1024), b256, 0, stream>>>(W, xT, blogT, mdT, s_part, 1);
    capsR<<<dim3(256), b256, 0, stream>>>(s_part, bias, out);
    capsB<<<dim3(1024), b256, 0, stream>>>(W, xT, out, blogT, 1);

    // ---- routing iteration 2 (final) ----
    capsD<<<dim3(1024), b256, 0, stream>>>(blogT, mdT);
    capsA<<<dim3(1024), b256, 0, stream>>>(W, xT, blogT, mdT, s_part, 1);
    capsR<<<dim3(256), b256, 0, stream>>>(s_part, bias, out);
}

// Round 8
// 168.246 us; speedup vs baseline: 1.2232x; 1.2232x over previous
//
#include <hip/hip_runtime.h>
#include <hip/hip_bf16.h>

// Problem constants
#define B_   128
#define J_   2048
#define N_   32
#define D_   16
#define NJC  32       // j-chunks (64 j each) for capsA s-partials

typedef __attribute__((ext_vector_type(8))) short short8b;   // 8 bf16 (4 VGPRs)
typedef __attribute__((ext_vector_type(4))) float f32x4;     // 16x16 MFMA acc
typedef __attribute__((ext_vector_type(16))) float f32x16;   // 32x32 MFMA acc

__device__ inline short bf16s(float f) {
    union { __hip_bfloat16 h; short s; } u;
    u.h = __float2bfloat16(f);
    return u.s;
}

// Workspace layout (float offsets):
//  xT     [0, 2097152)            xT[(j*128+b)*8 + p]          8 MB fp32
//  blogT  [2097152, 6291456)      blogT[(n*J+j)*128 + b]      16 MB bf16
//  mdT    [6291456, 6815744)      mdT[j*128 + b] float2        2 MB
//  s_part [6815744, 8912896)      [jc][b*512+n*16+d]           8 MB fp32
// total 34 MB

// ---------------------------------------------------------------------------
// T: xT[(j*128+b)*8+p] = x[b][j][p]   (LDS tile transpose)
// ---------------------------------------------------------------------------
__global__ __launch_bounds__(256) void capsT(const float* __restrict__ x,
                                             float* __restrict__ xT) {
    __shared__ float tile[32 * 260 + 4];
    const int t  = threadIdx.x;
    const int jt = blockIdx.x & 63;
    const int bt = blockIdx.x >> 6;
    const int j0 = jt * 32, b0 = bt * 32;

    for (int idx = t; idx < 2048; idx += 256) {
        int bl = idx >> 6, f4 = idx & 63;
        float4 v = *(const float4*)(x + (size_t)(b0 + bl) * 16384 + j0 * 8 + f4 * 4);
        *(float4*)&tile[bl * 260 + f4 * 4] = v;
    }
    __syncthreads();
    for (int idx = t; idx < 2048; idx += 256) {
        int jj = idx >> 6, f4o = idx & 63;
        int bl = f4o >> 1, po = (f4o & 1) * 4;
        float4 v = *(const float4*)&tile[bl * 260 + jj * 8 + po];
        *(float4*)(xT + ((size_t)(j0 + jj) * 128 + b0 + bl) * 8 + po) = v;
    }
}

// ---------------------------------------------------------------------------
// A (MFMA, unchanged from round 6): s_part[jc][b,n,d] = y(b,K) x W(K,d)
// ---------------------------------------------------------------------------
__global__ __launch_bounds__(256) void capsA(const float* __restrict__ W,
                                             const float* __restrict__ xT,
                                             const __hip_bfloat16* __restrict__ blogT,
                                             const float2* __restrict__ mdT,
                                             float* __restrict__ s_part,
                                             int mode) {
    const int t     = threadIdx.x;
    const int lane  = t & 63;
    const int i     = blockIdx.x;                    // 0..1023
    const int jc    = (i & 7) + 8 * (i >> 8);        // 0..31 (XCD-grouped)
    const int n     = (i >> 3) & 31;
    const int wv    = t >> 6;                        // 0..3
    const int colid = lane & 15;                     // d for B / b_low for A
    const int kgrp  = lane >> 4;                     // 0..3 -> j within K-step

    const int b0 = wv * 32 + colid;                  // A row, tile 0
    const int b1 = b0 + 16;                          // A row, tile 1

    f32x4 acc0 = {0.f, 0.f, 0.f, 0.f};
    f32x4 acc1 = {0.f, 0.f, 0.f, 0.f};

    for (int ks = 0; ks < 16; ++ks) {
        const int j = jc * 64 + ks * 4 + kgrp;       // per-lane j

        const float4* wp = (const float4*)(W + (((size_t)n * J_ + j) * 16 + colid) * 8);
        float4 wa = wp[0], wb = wp[1];
        short8b bfrag;
        bfrag[0] = bf16s(wa.x); bfrag[1] = bf16s(wa.y);
        bfrag[2] = bf16s(wa.z); bfrag[3] = bf16s(wa.w);
        bfrag[4] = bf16s(wb.x); bfrag[5] = bf16s(wb.y);
        bfrag[6] = bf16s(wb.z); bfrag[7] = bf16s(wb.w);

        float c0 = 1.0f / 32.0f, c1 = 1.0f / 32.0f;
        if (mode) {
            float lg0 = __bfloat162float(blogT[((size_t)n * J_ + j) * B_ + b0]);
            float lg1 = __bfloat162float(blogT[((size_t)n * J_ + j) * B_ + b1]);
            float2 m0 = mdT[(size_t)j * B_ + b0];
            float2 m1 = mdT[(size_t)j * B_ + b1];
            c0 = __expf(lg0 - m0.x) * m0.y;
            c1 = __expf(lg1 - m1.x) * m1.y;
        }

        const float4* xp0 = (const float4*)(xT + ((size_t)j * 128 + b0) * 8);
        float4 xa = xp0[0], xb = xp0[1];
        short8b afrag0;
        afrag0[0] = bf16s(xa.x * c0); afrag0[1] = bf16s(xa.y * c0);
        afrag0[2] = bf16s(xa.z * c0); afrag0[3] = bf16s(xa.w * c0);
        afrag0[4] = bf16s(xb.x * c0); afrag0[5] = bf16s(xb.y * c0);
        afrag0[6] = bf16s(xb.z * c0); afrag0[7] = bf16s(xb.w * c0);

        const float4* xp1 = (const float4*)(xT + ((size_t)j * 128 + b1) * 8);
        float4 xe = xp1[0], xf = xp1[1];
        short8b afrag1;
        afrag1[0] = bf16s(xe.x * c1); afrag1[1] = bf16s(xe.y * c1);
        afrag1[2] = bf16s(xe.z * c1); afrag1[3] = bf16s(xe.w * c1);
        afrag1[4] = bf16s(xf.x * c1); afrag1[5] = bf16s(xf.y * c1);
        afrag1[6] = bf16s(xf.z * c1); afrag1[7] = bf16s(xf.w * c1);

        acc0 = __builtin_amdgcn_mfma_f32_16x16x32_bf16(afrag0, bfrag, acc0, 0, 0, 0);
        acc1 = __builtin_amdgcn_mfma_f32_16x16x32_bf16(afrag1, bfrag, acc1, 0, 0, 0);
    }

    float* sdst = s_part + (size_t)jc * (B_ * N_ * D_);
    #pragma unroll
    for (int r = 0; r < 4; ++r) {
        int brow = wv * 32 + kgrp * 4 + r;
        sdst[(size_t)brow * 512 + n * 16 + colid]        = acc0[r];
        sdst[(size_t)(brow + 16) * 512 + n * 16 + colid] = acc1[r];
    }
}

// ---------------------------------------------------------------------------
// R: out[b,n,d] = squash(sum_jc s_part + bias)
// ---------------------------------------------------------------------------
__global__ __launch_bounds__(256) void capsR(const float* __restrict__ s_part,
                                             const float* __restrict__ bias,
                                             float* __restrict__ out) {
    int gid = blockIdx.x * 256 + threadIdx.x;       // 65536: b*512 + n*16 + d
    float sv = bias[gid & 511];
    #pragma unroll
    for (int jc = 0; jc < NJC; ++jc)
        sv += s_part[(size_t)jc * 65536 + gid];
    float sq = sv * sv;
    sq += __shfl_xor(sq, 1);
    sq += __shfl_xor(sq, 2);
    sq += __shfl_xor(sq, 4);
    sq += __shfl_xor(sq, 8);
    float scale = sq / (1.0f + sq) / sqrtf(sq + 1e-7f);
    out[gid] = scale * sv;
}

// ---------------------------------------------------------------------------
// B (MFMA v2): per (n, 32-j chunk): V[(j,p),b] = sum_d W[n,j,d,p]*o[b,n,d]
//   via mfma_f32_32x32x16_bf16, then blog = sum_p V*x on the D-frag.
//   Fixes vs round 7: W staged in LDS (pad-136 -> conflict-free afrag reads),
//   grid 2048 (2x waves), single live f32x16 acc (bt-loop with fused epilogue).
//   D layout (verified): col=lane&31 (b), row=(reg&3)+8*(reg>>2)+4*(lane>>5).
// ---------------------------------------------------------------------------
__global__ __launch_bounds__(256) void capsB(const float* __restrict__ W,
                                             const float* __restrict__ xT,
                                             const float* __restrict__ o,
                                             __hip_bfloat16* __restrict__ blogT,
                                             int accumulate) {
    __shared__ float w_lds[32 * 136];                    // 17.4 KB, pad-136 rows
    const int t    = threadIdx.x;
    const int lane = t & 63;
    const int i    = blockIdx.x;                         // 0..2047
    const int jc   = (i & 7) * 8 + (i >> 8);             // 0..63 (8 jc per XCD)
    const int n    = (i >> 3) & 31;
    const int wv   = t >> 6;                             // 0..3
    const int g    = lane >> 5;                          // k-half (d 0-7 / 8-15)
    const int col  = lane & 31;
    const int jl   = col >> 3;                           // j within 4-j group
    const int p    = col & 7;

    // ---- stage W chunk: 32 j-rows of 128 floats -> LDS rows of 136 ----
    {
        const float4* wsrc = (const float4*)(W + ((size_t)n * J_ + jc * 32) * 128);
        #pragma unroll
        for (int q = 0; q < 4; ++q) {
            int f = t + q * 256;                         // 0..1023 float4 units
            int row = f >> 5, c4 = f & 31;
            *(float4*)&w_lds[row * 136 + c4 * 4] = wsrc[f];
        }
    }

    // ---- B-fragments: o[b = bt*32+col][n][d = g*8 .. g*8+7] ----
    short8b bfrag[4];
    #pragma unroll
    for (int bt = 0; bt < 4; ++bt) {
        const float4* op =
            (const float4*)(o + ((size_t)(bt * 32 + col) * N_ + n) * 16 + g * 8);
        float4 oa = op[0], ob = op[1];
        bfrag[bt][0] = bf16s(oa.x); bfrag[bt][1] = bf16s(oa.y);
        bfrag[bt][2] = bf16s(oa.z); bfrag[bt][3] = bf16s(oa.w);
        bfrag[bt][4] = bf16s(ob.x); bfrag[bt][5] = bf16s(ob.y);
        bfrag[bt][6] = bf16s(ob.z); bfrag[bt][7] = bf16s(ob.w);
    }
    __syncthreads();

    f32x16 zz;
    #pragma unroll
    for (int q = 0; q < 16; ++q) zz[q] = 0.0f;

    #pragma unroll
    for (int jgi = 0; jgi < 2; ++jgi) {
        const int jg  = wv * 2 + jgi;                    // 0..7 (4-j group)
        const int j0  = jc * 32 + jg * 4;

        // ---- A-fragment from LDS: W[jg*4+jl][d=g*8+q][p], bank-conflict-free
        const float* wrow = w_lds + (jg * 4 + jl) * 136 + g * 64 + p;
        short8b afrag;
        #pragma unroll
        for (int q = 0; q < 8; ++q)
            afrag[q] = bf16s(wrow[q * 8]);

        #pragma unroll
        for (int bt = 0; bt < 4; ++bt) {
            f32x16 acc =
                __builtin_amdgcn_mfma_f32_32x32x16_bf16(afrag, bfrag[bt], zz, 0, 0, 0);
            const int b = bt * 32 + col;
            #pragma unroll
            for (int jl2 = 0; jl2 < 4; ++jl2) {
                const int j = j0 + jl2;
                float4 xv = *(const float4*)(xT + ((size_t)j * 128 + b) * 8 + g * 4);
                float tt = acc[jl2 * 4 + 0] * xv.x
                         + acc[jl2 * 4 + 1] * xv.y
                         + acc[jl2 * 4 + 2] * xv.z
                         + acc[jl2 * 4 + 3] * xv.w;
                tt += __shfl_xor(tt, 32);                // combine p halves
                if (g == (jl2 >> 1)) {                   // write-split across halves
                    size_t a0 = ((size_t)n * J_ + j) * B_ + b;
                    if (accumulate) tt += __bfloat162float(blogT[a0]);
                    blogT[a0] = __float2bfloat16(tt);
                }
            }
        }
    }
}

// ---------------------------------------------------------------------------
// D: per (j,b): m = max_n blogT, inv = 1/sum_n exp(blogT-m)
// ---------------------------------------------------------------------------
__global__ __launch_bounds__(256) void capsD(const __hip_bfloat16* __restrict__ blogT,
                                             float2* __restrict__ mdT) {
    int gid = blockIdx.x * 256 + threadIdx.x;   // 262144 = J_*B_
    float v[32];
    float m = -1e30f;
    #pragma unroll
    for (int nn = 0; nn < 32; ++nn) {
        v[nn] = __bfloat162float(blogT[(size_t)nn * (J_ * B_) + gid]);
        m = fmaxf(m, v[nn]);
    }
    float sum = 0.0f;
    #pragma unroll
    for (int nn = 0; nn < 32; ++nn) sum += __expf(v[nn] - m);
    mdT[gid] = make_float2(m, 1.0f / sum);
}

// ---------------------------------------------------------------------------
extern "C" void kernel_launch(void* const* d_in, const int* in_sizes, int n_in,
                              void* d_out, int out_size, void* d_ws, size_t ws_size,
                              hipStream_t stream) {
    const float* x    = (const float*)d_in[0];   // [128,2048,8]
    const float* W    = (const float*)d_in[1];   // [32,2048,16,8]
    const float* bias = (const float*)d_in[2];   // [32,16]
    float* out = (float*)d_out;                  // [128,32,16]

    float* ws = (float*)d_ws;
    float*           xT     = ws;                                   // 8 MB
    __hip_bfloat16*  blogT  = (__hip_bfloat16*)(ws + 2097152);      // 16 MB bf16
    float2*          mdT    = (float2*)(ws + 2097152 + 4194304);    // 2 MB
    float*           s_part = ws + 2097152 + 4194304 + 524288;      // 8 MB

    dim3 b256(256);

    capsT<<<dim3(256), b256, 0, stream>>>(x, xT);

    // ---- routing iteration 0 (c uniform) ----
    capsA<<<dim3(1024), b256, 0, stream>>>(W, xT, blogT, mdT, s_part, 0);
    capsR<<<dim3(256), b256, 0, stream>>>(s_part, bias, out);
    capsB<<<dim3(2048), b256, 0, stream>>>(W, xT, out, blogT, 0);

    // ---- routing iteration 1 ----
    capsD<<<dim3(1024), b256, 0, stream>>>(blogT, mdT);
    capsA<<<dim3(1024), b256, 0, stream>>>(W, xT, blogT, mdT, s_part, 1);
    capsR<<<dim3(256), b256, 0, stream>>>(s_part, bias, out);
    capsB<<<dim3(2048), b256, 0, stream>>>(W, xT, out, blogT, 1);

    // ---- routing iteration 2 (final) ----
    capsD<<<dim3(1024), b256, 0, stream>>>(blogT, mdT);
    capsA<<<dim3(1024), b256, 0, stream>>>(W, xT, blogT, mdT, s_part, 1);
    capsR<<<dim3(256), b256, 0, stream>>>(s_part, bias, out);
}

// Round 11
// 144.671 us; speedup vs baseline: 1.4226x; 1.1630x over previous
//
#include <hip/hip_runtime.h>
#include <hip/hip_bf16.h>

// Problem constants
#define B_   128
#define J_   2048
#define N_   32
#define D_   16
#define NJC  32       // j-chunks (64 j each) for capsA s-partials

typedef __attribute__((ext_vector_type(8))) short short8b;   // 8 bf16 (4 VGPRs)
typedef __attribute__((ext_vector_type(4))) float f32x4;     // 16x16 MFMA acc
typedef __attribute__((ext_vector_type(16))) float f32x16;   // 32x32 MFMA acc

__device__ inline short bf16s(float f) {
    union { __hip_bfloat16 h; short s; } u;
    u.h = __float2bfloat16(f);
    return u.s;
}

// Workspace layout (float offsets):
//  xT     [0, 2097152)            xT[(j*128+b)*8 + p]          8 MB fp32
//  blogT  [2097152, 6291456)      blogT[(n*J+j)*128 + b]      16 MB bf16
//  mdT    [6291456, 6815744)      mdT[j*128 + b] float2        2 MB
//  s_part [6815744, 8912896)      [jc][b*512+n*16+d]           8 MB fp32
//  oT     [8912896, 8945664)      oT[n*128+b][d] bf16        128 KB
// total 34.13 MB

// ---------------------------------------------------------------------------
// T: xT[(j*128+b)*8+p] = x[b][j][p]   (LDS tile transpose)
// ---------------------------------------------------------------------------
__global__ __launch_bounds__(256) void capsT(const float* __restrict__ x,
                                             float* __restrict__ xT) {
    __shared__ float tile[32 * 260 + 4];
    const int t  = threadIdx.x;
    const int jt = blockIdx.x & 63;
    const int bt = blockIdx.x >> 6;
    const int j0 = jt * 32, b0 = bt * 32;

    for (int idx = t; idx < 2048; idx += 256) {
        int bl = idx >> 6, f4 = idx & 63;
        float4 v = *(const float4*)(x + (size_t)(b0 + bl) * 16384 + j0 * 8 + f4 * 4);
        *(float4*)&tile[bl * 260 + f4 * 4] = v;
    }
    __syncthreads();
    for (int idx = t; idx < 2048; idx += 256) {
        int jj = idx >> 6, f4o = idx & 63;
        int bl = f4o >> 1, po = (f4o & 1) * 4;
        float4 v = *(const float4*)&tile[bl * 260 + jj * 8 + po];
        *(float4*)(xT + ((size_t)(j0 + jj) * 128 + b0 + bl) * 8 + po) = v;
    }
}

// ---------------------------------------------------------------------------
// A (MFMA, unchanged from round 6): s_part[jc][b,n,d] = y(b,K) x W(K,d)
// ---------------------------------------------------------------------------
__global__ __launch_bounds__(256) void capsA(const float* __restrict__ W,
                                             const float* __restrict__ xT,
                                             const __hip_bfloat16* __restrict__ blogT,
                                             const float2* __restrict__ mdT,
                                             float* __restrict__ s_part,
                                             int mode) {
    const int t     = threadIdx.x;
    const int lane  = t & 63;
    const int i     = blockIdx.x;                    // 0..1023
    const int jc    = (i & 7) + 8 * (i >> 8);        // 0..31 (XCD-grouped)
    const int n     = (i >> 3) & 31;
    const int wv    = t >> 6;                        // 0..3
    const int colid = lane & 15;                     // d for B / b_low for A
    const int kgrp  = lane >> 4;                     // 0..3 -> j within K-step

    const int b0 = wv * 32 + colid;                  // A row, tile 0
    const int b1 = b0 + 16;                          // A row, tile 1

    f32x4 acc0 = {0.f, 0.f, 0.f, 0.f};
    f32x4 acc1 = {0.f, 0.f, 0.f, 0.f};

    for (int ks = 0; ks < 16; ++ks) {
        const int j = jc * 64 + ks * 4 + kgrp;       // per-lane j

        const float4* wp = (const float4*)(W + (((size_t)n * J_ + j) * 16 + colid) * 8);
        float4 wa = wp[0], wb = wp[1];
        short8b bfrag;
        bfrag[0] = bf16s(wa.x); bfrag[1] = bf16s(wa.y);
        bfrag[2] = bf16s(wa.z); bfrag[3] = bf16s(wa.w);
        bfrag[4] = bf16s(wb.x); bfrag[5] = bf16s(wb.y);
        bfrag[6] = bf16s(wb.z); bfrag[7] = bf16s(wb.w);

        float c0 = 1.0f / 32.0f, c1 = 1.0f / 32.0f;
        if (mode) {
            float lg0 = __bfloat162float(blogT[((size_t)n * J_ + j) * B_ + b0]);
            float lg1 = __bfloat162float(blogT[((size_t)n * J_ + j) * B_ + b1]);
            float2 m0 = mdT[(size_t)j * B_ + b0];
            float2 m1 = mdT[(size_t)j * B_ + b1];
            c0 = __expf(lg0 - m0.x) * m0.y;
            c1 = __expf(lg1 - m1.x) * m1.y;
        }

        const float4* xp0 = (const float4*)(xT + ((size_t)j * 128 + b0) * 8);
        float4 xa = xp0[0], xb = xp0[1];
        short8b afrag0;
        afrag0[0] = bf16s(xa.x * c0); afrag0[1] = bf16s(xa.y * c0);
        afrag0[2] = bf16s(xa.z * c0); afrag0[3] = bf16s(xa.w * c0);
        afrag0[4] = bf16s(xb.x * c0); afrag0[5] = bf16s(xb.y * c0);
        afrag0[6] = bf16s(xb.z * c0); afrag0[7] = bf16s(xb.w * c0);

        const float4* xp1 = (const float4*)(xT + ((size_t)j * 128 + b1) * 8);
        float4 xe = xp1[0], xf = xp1[1];
        short8b afrag1;
        afrag1[0] = bf16s(xe.x * c1); afrag1[1] = bf16s(xe.y * c1);
        afrag1[2] = bf16s(xe.z * c1); afrag1[3] = bf16s(xe.w * c1);
        afrag1[4] = bf16s(xf.x * c1); afrag1[5] = bf16s(xf.y * c1);
        afrag1[6] = bf16s(xf.z * c1); afrag1[7] = bf16s(xf.w * c1);

        acc0 = __builtin_amdgcn_mfma_f32_16x16x32_bf16(afrag0, bfrag, acc0, 0, 0, 0);
        acc1 = __builtin_amdgcn_mfma_f32_16x16x32_bf16(afrag1, bfrag, acc1, 0, 0, 0);
    }

    float* sdst = s_part + (size_t)jc * (B_ * N_ * D_);
    #pragma unroll
    for (int r = 0; r < 4; ++r) {
        int brow = wv * 32 + kgrp * 4 + r;
        sdst[(size_t)brow * 512 + n * 16 + colid]        = acc0[r];
        sdst[(size_t)(brow + 16) * 512 + n * 16 + colid] = acc1[r];
    }
}

// ---------------------------------------------------------------------------
// R: out[b,n,d] = squash(sum_jc s_part + bias); also emit oT bf16 for capsB
// ---------------------------------------------------------------------------
__global__ __launch_bounds__(256) void capsR(const float* __restrict__ s_part,
                                             const float* __restrict__ bias,
                                             float* __restrict__ out,
                                             __hip_bfloat16* __restrict__ oT) {
    int gid = blockIdx.x * 256 + threadIdx.x;       // 65536: b*512 + n*16 + d
    float sv = bias[gid & 511];
    #pragma unroll
    for (int jc = 0; jc < NJC; ++jc)
        sv += s_part[(size_t)jc * 65536 + gid];
    float sq = sv * sv;
    sq += __shfl_xor(sq, 1);
    sq += __shfl_xor(sq, 2);
    sq += __shfl_xor(sq, 4);
    sq += __shfl_xor(sq, 8);
    float scale = sq / (1.0f + sq) / sqrtf(sq + 1e-7f);
    float ov = scale * sv;
    out[gid] = ov;
    int b = gid >> 9, nd = gid & 511;
    int n = nd >> 4, d = nd & 15;
    oT[((size_t)n * B_ + b) * D_ + d] = __float2bfloat16(ov);
}

// ---------------------------------------------------------------------------
// B (MFMA v5): block = (4 j, 128 b, 16 n); wave wv OWNS b-tile bt=wv ->
//   disjoint blogT writes (fixes the v3/v4 cross-wave accumulate race).
//   All 16 n's W staged up-front in LDS (pad-136 rows, conflict-free),
//   ONE barrier total, no in-loop barriers. xv direct from L2-resident xT.
//   Per n: V[(j,p),b]=sum_d W*o via mfma_f32_32x32x16_bf16; blog=sum_p V*x.
//   D layout (verified): col=lane&31 (b), row=(reg&3)+8*(reg>>2)+4*(lane>>5).
// ---------------------------------------------------------------------------
__global__ __launch_bounds__(256) void capsB(const float* __restrict__ W,
                                             const float* __restrict__ xT,
                                             const __hip_bfloat16* __restrict__ oT,
                                             __hip_bfloat16* __restrict__ blogT,
                                             int accumulate) {
    __shared__ float w_lds[16 * 544];         // 34.8 KB: [nn][jl*136 + d*8 + p]
    const int t    = threadIdx.x;
    const int lane = t & 63;
    const int i    = blockIdx.x;              // 0..1023
    const int xcd  = i & 7;
    const int r    = i >> 3;                  // 0..127
    const int jq   = xcd * 64 + (r & 63);     // 0..511 (XCD owns 256 j)
    const int nh   = r >> 6;                  // 0..1
    const int j0   = jq * 4;
    const int wv   = t >> 6;                  // 0..3  -> owned b-tile
    const int g    = lane >> 5;               // k-half (d 0-7 / 8-15)
    const int col  = lane & 31;
    const int jl   = col >> 3;                // j within quad (A-row)
    const int p    = col & 7;
    const int bt   = wv;                      // wave-owned b-tile (race-free)

    // ---- stage W for ALL 16 n: 2048 float4 = 32 KB, coalesced ----
    #pragma unroll
    for (int q = 0; q < 8; ++q) {
        int f = t + q * 256;                  // 0..2047
        int n_idx = f >> 7;                   // 0..15
        int rem = f & 127;
        int row = rem >> 5, c4 = rem & 31;
        float4 v = *(const float4*)(W + ((size_t)(nh * 16 + n_idx) * J_ + j0 + row) * 128 + c4 * 4);
        *(float4*)&w_lds[n_idx * 544 + row * 136 + c4 * 4] = v;
    }
    __syncthreads();                          // the only barrier

    // ---- epilogue x operands: own b-tile only, 4 float4 in VGPRs ----
    float4 xv[4];
    #pragma unroll
    for (int jl2 = 0; jl2 < 4; ++jl2)
        xv[jl2] = *(const float4*)(xT + ((size_t)(j0 + jl2) * 128 + bt * 32 + col) * 8 + g * 4);

    f32x16 zz;
    #pragma unroll
    for (int q = 0; q < 16; ++q) zz[q] = 0.0f;

    for (int nn = 0; nn < 16; ++nn) {
        const int n = nh * 16 + nn;

        // ---- B-fragment: oT[n][b = bt*32+col][d = g*8..] single 16B load ----
        short8b bfrag = *(const short8b*)(oT + ((size_t)n * B_ + bt * 32 + col) * D_ + g * 8);

        // ---- A-fragment: w_lds[nn][jl][d=g*8+q][p] (pad-136: conflict-free) ----
        const float* wrow = &w_lds[nn * 544 + jl * 136 + g * 64 + p];
        short8b afrag;
        #pragma unroll
        for (int q = 0; q < 8; ++q)
            afrag[q] = bf16s(wrow[q * 8]);

        f32x16 acc =
            __builtin_amdgcn_mfma_f32_32x32x16_bf16(afrag, bfrag, zz, 0, 0, 0);

        const int b = bt * 32 + col;
        #pragma unroll
        for (int jl2 = 0; jl2 < 4; ++jl2) {
            const int j = j0 + jl2;
            float4 v = xv[jl2];
            float tt = acc[jl2 * 4 + 0] * v.x
                     + acc[jl2 * 4 + 1] * v.y
                     + acc[jl2 * 4 + 2] * v.z
                     + acc[jl2 * 4 + 3] * v.w;
            tt += __shfl_xor(tt, 32);                // combine p halves
            if (g == (jl2 >> 1)) {                   // write-split across halves
                size_t a0 = ((size_t)n * J_ + j) * B_ + b;
                if (accumulate) tt += __bfloat162float(blogT[a0]);
                blogT[a0] = __float2bfloat16(tt);
            }
        }
    }
}

// ---------------------------------------------------------------------------
// D: per (j,b): m = max_n blogT, inv = 1/sum_n exp(blogT-m)
// ---------------------------------------------------------------------------
__global__ __launch_bounds__(256) void capsD(const __hip_bfloat16* __restrict__ blogT,
                                             float2* __restrict__ mdT) {
    int gid = blockIdx.x * 256 + threadIdx.x;   // 262144 = J_*B_
    float v[32];
    float m = -1e30f;
    #pragma unroll
    for (int nn = 0; nn < 32; ++nn) {
        v[nn] = __bfloat162float(blogT[(size_t)nn * (J_ * B_) + gid]);
        m = fmaxf(m, v[nn]);
    }
    float sum = 0.0f;
    #pragma unroll
    for (int nn = 0; nn < 32; ++nn) sum += __expf(v[nn] - m);
    mdT[gid] = make_float2(m, 1.0f / sum);
}

// ---------------------------------------------------------------------------
extern "C" void kernel_launch(void* const* d_in, const int* in_sizes, int n_in,
                              void* d_out, int out_size, void* d_ws, size_t ws_size,
                              hipStream_t stream) {
    const float* x    = (const float*)d_in[0];   // [128,2048,8]
    const float* W    = (const float*)d_in[1];   // [32,2048,16,8]
    const float* bias = (const float*)d_in[2];   // [32,16]
    float* out = (float*)d_out;                  // [128,32,16]

    float* ws = (float*)d_ws;
    float*           xT     = ws;                                   // 8 MB
    __hip_bfloat16*  blogT  = (__hip_bfloat16*)(ws + 2097152);      // 16 MB bf16
    float2*          mdT    = (float2*)(ws + 2097152 + 4194304);    // 2 MB
    float*           s_part = ws + 2097152 + 4194304 + 524288;      // 8 MB
    __hip_bfloat16*  oT     = (__hip_bfloat16*)(ws + 8912896);      // 128 KB

    dim3 b256(256);

    capsT<<<dim3(256), b256, 0, stream>>>(x, xT);

    // ---- routing iteration 0 (c uniform) ----
    capsA<<<dim3(1024), b256, 0, stream>>>(W, xT, blogT, mdT, s_part, 0);
    capsR<<<dim3(256), b256, 0, stream>>>(s_part, bias, out, oT);
    capsB<<<dim3(1024), b256, 0, stream>>>(W, xT, oT, blogT, 0);

    // ---- routing iteration 1 ----
    capsD<<<dim3(1024), b256, 0, stream>>>(blogT, mdT);
    capsA<<<dim3(1024), b256, 0, stream>>>(W, xT, blogT, mdT, s_part, 1);
    capsR<<<dim3(256), b256, 0, stream>>>(s_part, bias, out, oT);
    capsB<<<dim3(1024), b256, 0, stream>>>(W, xT, oT, blogT, 1);

    // ---- routing iteration 2 (final) ----
    capsD<<<dim3(1024), b256, 0, stream>>>(blogT, mdT);
    capsA<<<dim3(1024), b256, 0, stream>>>(W, xT, blogT, mdT, s_part, 1);
    capsR<<<dim3(256), b256, 0, stream>>>(s_part, bias, out, oT);
}

// Round 12
// 141.230 us; speedup vs baseline: 1.4572x; 1.0244x over previous
//
#include <hip/hip_runtime.h>
#include <hip/hip_bf16.h>

// Problem constants
#define B_   128
#define J_   2048
#define N_   32
#define D_   16
#define NJC  32       // j-chunks (64 j each) for capsA s-partials

typedef __attribute__((ext_vector_type(8))) short short8b;   // 8 bf16 (4 VGPRs)
typedef __attribute__((ext_vector_type(4))) float f32x4;     // 16x16 MFMA acc
typedef __attribute__((ext_vector_type(16))) float f32x16;   // 32x32 MFMA acc

__device__ inline short bf16s(float f) {
    union { __hip_bfloat16 h; short s; } u;
    u.h = __float2bfloat16(f);
    return u.s;
}

// Workspace layout (float offsets), ws_size ~256 MiB:
//  xT     [0, 2097152)             xT[(j*128+b)*8 + p]          8 MB fp32
//  blogT  [2097152, 6291456)       blogT[(n*J+j)*128 + b]     16 MB bf16
//  cT     [6291456, 10485760)      cT[(n*J+j)*128 + b]        16 MB bf16
//  s_part [10485760, 12582912)     [jc][b*512+n*16+d]          8 MB fp32
//  oT     [12582912, 12615680)     oT[(n*128+b)*16 + d]      128 KB bf16
//  Wbf    [12615680, 16809984)     W bf16, layout [n][j][d][p] 16 MB
//  Wt     [16809984, 21004288)     W bf16, layout [n][j][p][d] 16 MB
// total 84 MB

// ---------------------------------------------------------------------------
// W: one-time W fp32 -> bf16 in two layouts (Wbf straight, Wt d<->p transposed)
//    grid 4096: each block converts 16 (n,j) rows of 128 elements.
// ---------------------------------------------------------------------------
__global__ __launch_bounds__(256) void capsW(const float* __restrict__ W,
                                             __hip_bfloat16* __restrict__ Wbf,
                                             __hip_bfloat16* __restrict__ Wt) {
    __shared__ float lds[16 * 132];
    const int t = threadIdx.x;
    const size_t base = (size_t)blockIdx.x * 2048;   // 16 rows x 128 elems
    const int r  = t >> 4;                           // row 0..15
    const int e0 = (t & 15) * 8;                     // elem offset within row

    float4 a = *(const float4*)(W + base + t * 8);
    float4 b = *(const float4*)(W + base + t * 8 + 4);
    short8b w8;
    w8[0]=bf16s(a.x); w8[1]=bf16s(a.y); w8[2]=bf16s(a.z); w8[3]=bf16s(a.w);
    w8[4]=bf16s(b.x); w8[5]=bf16s(b.y); w8[6]=bf16s(b.z); w8[7]=bf16s(b.w);
    *(short8b*)((short*)Wbf + base + t * 8) = w8;
    *(float4*)&lds[r * 132 + e0]     = a;
    *(float4*)&lds[r * 132 + e0 + 4] = b;
    __syncthreads();

    short8b o8;
    #pragma unroll
    for (int k = 0; k < 8; ++k) {
        int q = e0 + k;                 // Wt within-row index = p*16 + d
        int p = q >> 4, d = q & 15;
        o8[k] = bf16s(lds[r * 132 + d * 8 + p]);
    }
    *(short8b*)((short*)Wt + base + t * 8) = o8;
}

// ---------------------------------------------------------------------------
// T: xT[(j*128+b)*8+p] = x[b][j][p]   (LDS tile transpose)
// ---------------------------------------------------------------------------
__global__ __launch_bounds__(256) void capsT(const float* __restrict__ x,
                                             float* __restrict__ xT) {
    __shared__ float tile[32 * 260 + 4];
    const int t  = threadIdx.x;
    const int jt = blockIdx.x & 63;
    const int bt = blockIdx.x >> 6;
    const int j0 = jt * 32, b0 = bt * 32;

    for (int idx = t; idx < 2048; idx += 256) {
        int bl = idx >> 6, f4 = idx & 63;
        float4 v = *(const float4*)(x + (size_t)(b0 + bl) * 16384 + j0 * 8 + f4 * 4);
        *(float4*)&tile[bl * 260 + f4 * 4] = v;
    }
    __syncthreads();
    for (int idx = t; idx < 2048; idx += 256) {
        int jj = idx >> 6, f4o = idx & 63;
        int bl = f4o >> 1, po = (f4o & 1) * 4;
        float4 v = *(const float4*)&tile[bl * 260 + jj * 8 + po];
        *(float4*)(xT + ((size_t)(j0 + jj) * 128 + b0 + bl) * 8 + po) = v;
    }
}

// ---------------------------------------------------------------------------
// A (MFMA v2): s_part[jc][b,n,d] = y(b,K) x W(K,d);  W from Wbf (bf16 direct),
//   c from cT (bf16 direct, no exp). Geometry/layouts = round-11 (verified).
// ---------------------------------------------------------------------------
__global__ __launch_bounds__(256) void capsA(const __hip_bfloat16* __restrict__ Wbf,
                                             const float* __restrict__ xT,
                                             const __hip_bfloat16* __restrict__ cT,
                                             float* __restrict__ s_part,
                                             int mode) {
    const int t     = threadIdx.x;
    const int lane  = t & 63;
    const int i     = blockIdx.x;                    // 0..1023
    const int jc    = (i & 7) + 8 * (i >> 8);        // 0..31 (XCD-grouped)
    const int n     = (i >> 3) & 31;
    const int wv    = t >> 6;                        // 0..3
    const int colid = lane & 15;                     // d for B / b_low for A
    const int kgrp  = lane >> 4;                     // 0..3 -> j within K-step

    const int b0 = wv * 32 + colid;                  // A row, tile 0
    const int b1 = b0 + 16;                          // A row, tile 1

    f32x4 acc0 = {0.f, 0.f, 0.f, 0.f};
    f32x4 acc1 = {0.f, 0.f, 0.f, 0.f};

    for (int ks = 0; ks < 16; ++ks) {
        const int j = jc * 64 + ks * 4 + kgrp;       // per-lane j

        // ---- B-fragment: direct bf16 16B load (coalesced) ----
        short8b bfrag = *(const short8b*)((const short*)Wbf
                          + (((size_t)n * J_ + j) * 16 + colid) * 8);

        float c0 = 1.0f / 32.0f, c1 = 1.0f / 32.0f;
        if (mode) {
            c0 = __bfloat162float(cT[((size_t)n * J_ + j) * B_ + b0]);
            c1 = __bfloat162float(cT[((size_t)n * J_ + j) * B_ + b1]);
        }

        const float4* xp0 = (const float4*)(xT + ((size_t)j * 128 + b0) * 8);
        float4 xa = xp0[0], xb = xp0[1];
        short8b afrag0;
        afrag0[0] = bf16s(xa.x * c0); afrag0[1] = bf16s(xa.y * c0);
        afrag0[2] = bf16s(xa.z * c0); afrag0[3] = bf16s(xa.w * c0);
        afrag0[4] = bf16s(xb.x * c0); afrag0[5] = bf16s(xb.y * c0);
        afrag0[6] = bf16s(xb.z * c0); afrag0[7] = bf16s(xb.w * c0);

        const float4* xp1 = (const float4*)(xT + ((size_t)j * 128 + b1) * 8);
        float4 xe = xp1[0], xf = xp1[1];
        short8b afrag1;
        afrag1[0] = bf16s(xe.x * c1); afrag1[1] = bf16s(xe.y * c1);
        afrag1[2] = bf16s(xe.z * c1); afrag1[3] = bf16s(xe.w * c1);
        afrag1[4] = bf16s(xf.x * c1); afrag1[5] = bf16s(xf.y * c1);
        afrag1[6] = bf16s(xf.z * c1); afrag1[7] = bf16s(xf.w * c1);

        acc0 = __builtin_amdgcn_mfma_f32_16x16x32_bf16(afrag0, bfrag, acc0, 0, 0, 0);
        acc1 = __builtin_amdgcn_mfma_f32_16x16x32_bf16(afrag1, bfrag, acc1, 0, 0, 0);
    }

    float* sdst = s_part + (size_t)jc * (B_ * N_ * D_);
    #pragma unroll
    for (int r = 0; r < 4; ++r) {
        int brow = wv * 32 + kgrp * 4 + r;
        sdst[(size_t)brow * 512 + n * 16 + colid]        = acc0[r];
        sdst[(size_t)(brow + 16) * 512 + n * 16 + colid] = acc1[r];
    }
}

// ---------------------------------------------------------------------------
// R: out[b,n,d] = squash(sum_jc s_part + bias); also emit oT bf16 for capsB
// ---------------------------------------------------------------------------
__global__ __launch_bounds__(256) void capsR(const float* __restrict__ s_part,
                                             const float* __restrict__ bias,
                                             float* __restrict__ out,
                                             __hip_bfloat16* __restrict__ oT) {
    int gid = blockIdx.x * 256 + threadIdx.x;       // 65536: b*512 + n*16 + d
    float sv = bias[gid & 511];
    #pragma unroll
    for (int jc = 0; jc < NJC; ++jc)
        sv += s_part[(size_t)jc * 65536 + gid];
    float sq = sv * sv;
    sq += __shfl_xor(sq, 1);
    sq += __shfl_xor(sq, 2);
    sq += __shfl_xor(sq, 4);
    sq += __shfl_xor(sq, 8);
    float scale = sq / (1.0f + sq) / sqrtf(sq + 1e-7f);
    float ov = scale * sv;
    out[gid] = ov;
    int b = gid >> 9, nd = gid & 511;
    int n = nd >> 4, d = nd & 15;
    oT[((size_t)n * B_ + b) * D_ + d] = __float2bfloat16(ov);
}

// ---------------------------------------------------------------------------
// B (MFMA v6): round-11 v5 geometry (bt=wv, race-free), but afrag comes as a
//   single 16B load from pre-transposed Wt -> NO LDS, NO barriers at all.
//   Per n: V[(j,p),b]=sum_d W*o via mfma_f32_32x32x16_bf16; blog=sum_p V*x.
// ---------------------------------------------------------------------------
__global__ __launch_bounds__(256) void capsB(const __hip_bfloat16* __restrict__ Wt,
                                             const float* __restrict__ xT,
                                             const __hip_bfloat16* __restrict__ oT,
                                             __hip_bfloat16* __restrict__ blogT,
                                             int accumulate) {
    const int t    = threadIdx.x;
    const int lane = t & 63;
    const int i    = blockIdx.x;              // 0..1023
    const int xcd  = i & 7;
    const int r    = i >> 3;                  // 0..127
    const int jq   = xcd * 64 + (r & 63);     // 0..511 (XCD owns 256 j)
    const int nh   = r >> 6;                  // 0..1
    const int j0   = jq * 4;
    const int wv   = t >> 6;                  // 0..3  -> owned b-tile
    const int g    = lane >> 5;               // k-half (d 0-7 / 8-15)
    const int col  = lane & 31;
    const int jl   = col >> 3;                // j within quad (A-row)
    const int p    = col & 7;
    const int bt   = wv;                      // wave-owned b-tile (race-free)

    // ---- epilogue x operands: own b-tile only, 4 float4 in VGPRs ----
    float4 xv[4];
    #pragma unroll
    for (int jl2 = 0; jl2 < 4; ++jl2)
        xv[jl2] = *(const float4*)(xT + ((size_t)(j0 + jl2) * 128 + bt * 32 + col) * 8 + g * 4);

    f32x16 zz;
    #pragma unroll
    for (int q = 0; q < 16; ++q) zz[q] = 0.0f;

    #pragma unroll 2
    for (int nn = 0; nn < 16; ++nn) {
        const int n = nh * 16 + nn;

        // ---- B-fragment: oT[n][b = bt*32+col][d = g*8..] single 16B load ----
        short8b bfrag = *(const short8b*)(oT + ((size_t)n * B_ + bt * 32 + col) * D_ + g * 8);

        // ---- A-fragment: Wt[n][j0+jl][p][d = g*8..] single 16B load ----
        short8b afrag = *(const short8b*)((const short*)Wt
                          + (((size_t)n * J_ + j0 + jl) * 8 + p) * 16 + g * 8);

        f32x16 acc =
            __builtin_amdgcn_mfma_f32_32x32x16_bf16(afrag, bfrag, zz, 0, 0, 0);

        const int b = bt * 32 + col;
        #pragma unroll
        for (int jl2 = 0; jl2 < 4; ++jl2) {
            const int j = j0 + jl2;
            float4 v = xv[jl2];
            float tt = acc[jl2 * 4 + 0] * v.x
                     + acc[jl2 * 4 + 1] * v.y
                     + acc[jl2 * 4 + 2] * v.z
                     + acc[jl2 * 4 + 3] * v.w;
            tt += __shfl_xor(tt, 32);                // combine p halves
            if (g == (jl2 >> 1)) {                   // write-split across halves
                size_t a0 = ((size_t)n * J_ + j) * B_ + b;
                if (accumulate) tt += __bfloat162float(blogT[a0]);
                blogT[a0] = __float2bfloat16(tt);
            }
        }
    }
}

// ---------------------------------------------------------------------------
// D (v2): per (j,b): softmax over n of blogT -> cT bf16 (consumed by capsA)
// ---------------------------------------------------------------------------
__global__ __launch_bounds__(256) void capsD(const __hip_bfloat16* __restrict__ blogT,
                                             __hip_bfloat16* __restrict__ cT) {
    int gid = blockIdx.x * 256 + threadIdx.x;   // 262144 = J_*B_ (j*128+b)
    float v[32];
    float m = -1e30f;
    #pragma unroll
    for (int nn = 0; nn < 32; ++nn) {
        v[nn] = __bfloat162float(blogT[(size_t)nn * (J_ * B_) + gid]);
        m = fmaxf(m, v[nn]);
    }
    float sum = 0.0f;
    #pragma unroll
    for (int nn = 0; nn < 32; ++nn) sum += __expf(v[nn] - m);
    float inv = 1.0f / sum;
    #pragma unroll
    for (int nn = 0; nn < 32; ++nn)
        cT[(size_t)nn * (J_ * B_) + gid] = __float2bfloat16(__expf(v[nn] - m) * inv);
}

// ---------------------------------------------------------------------------
extern "C" void kernel_launch(void* const* d_in, const int* in_sizes, int n_in,
                              void* d_out, int out_size, void* d_ws, size_t ws_size,
                              hipStream_t stream) {
    const float* x    = (const float*)d_in[0];   // [128,2048,8]
    const float* W    = (const float*)d_in[1];   // [32,2048,16,8]
    const float* bias = (const float*)d_in[2];   // [32,16]
    float* out = (float*)d_out;                  // [128,32,16]

    float* ws = (float*)d_ws;
    float*           xT     = ws;                                    // 8 MB
    __hip_bfloat16*  blogT  = (__hip_bfloat16*)(ws + 2097152);       // 16 MB
    __hip_bfloat16*  cT     = (__hip_bfloat16*)(ws + 6291456);       // 16 MB
    float*           s_part = ws + 10485760;                         // 8 MB
    __hip_bfloat16*  oT     = (__hip_bfloat16*)(ws + 12582912);      // 128 KB
    __hip_bfloat16*  Wbf    = (__hip_bfloat16*)(ws + 12615680);      // 16 MB
    __hip_bfloat16*  Wt     = (__hip_bfloat16*)(ws + 16809984);      // 16 MB

    dim3 b256(256);

    capsW<<<dim3(4096), b256, 0, stream>>>(W, Wbf, Wt);
    capsT<<<dim3(256),  b256, 0, stream>>>(x, xT);

    // ---- routing iteration 0 (c uniform) ----
    capsA<<<dim3(1024), b256, 0, stream>>>(Wbf, xT, cT, s_part, 0);
    capsR<<<dim3(256),  b256, 0, stream>>>(s_part, bias, out, oT);
    capsB<<<dim3(1024), b256, 0, stream>>>(Wt, xT, oT, blogT, 0);

    // ---- routing iteration 1 ----
    capsD<<<dim3(1024), b256, 0, stream>>>(blogT, cT);
    capsA<<<dim3(1024), b256, 0, stream>>>(Wbf, xT, cT, s_part, 1);
    capsR<<<dim3(256),  b256, 0, stream>>>(s_part, bias, out, oT);
    capsB<<<dim3(1024), b256, 0, stream>>>(Wt, xT, oT, blogT, 1);

    // ---- routing iteration 2 (final) ----
    capsD<<<dim3(1024), b256, 0, stream>>>(blogT, cT);
    capsA<<<dim3(1024), b256, 0, stream>>>(Wbf, xT, cT, s_part, 1);
    capsR<<<dim3(256),  b256, 0, stream>>>(s_part, bias, out, oT);
}